// Round 10
// baseline (151.141 us; speedup 1.0000x reference)
//
#include <hip/hip_runtime.h>
#include <stdint.h>

#define N_BOX 1024
#define C_CLS 80
#define B_IMG 4
#define K_PER 100
#define K_TOT 300
#define NEGF  (-1e30f)
#define NWORD 16                 // 1024 bits / 64
#define NCAND (C_CLS * K_PER)    // 8000 candidates per image
#define M_SEL 8192               // flat-index packing base for final top-k

// workspace layout (bytes) — 4,713,728 total (round-7 proven footprint)
#define OFF_SCOREST 0            // [B][C][N] f32          1,310,720
#define OFF_MASKS   1310720      // [B][N][NWORD] u64        524,288
#define OFF_SORTED  1835008      // [B*C][N] u64           2,621,440
#define OFF_NVALID  4456448      // [B*C] i32                  1,280
#define OFF_WSCORE  4457728      // [B*C][K_PER] f32         128,000
#define OFF_WSIDX   4585728      // [B*C][K_PER] i32         128,000

typedef unsigned long long u64;
typedef unsigned int u32;

// ---- monotone float <-> ordered-uint mapping (total order, bit-exact) ----
__device__ __forceinline__ u32 ford(float f) {
    u32 u = __float_as_uint(f);
    return (u & 0x80000000u) ? ~u : (u | 0x80000000u);
}
__device__ __forceinline__ float funord(u32 o) {
    u32 u = (o & 0x80000000u) ? (o ^ 0x80000000u) : ~o;
    return __uint_as_float(u);
}

// IoU matching the numpy/jax float32 arithmetic exactly: no fma contraction.
__device__ __forceinline__ float iou_f(float4 a, float4 b) {
#pragma clang fp contract(off)
    float y1a = fminf(a.x, a.z), y2a = fmaxf(a.x, a.z);
    float x1a = fminf(a.y, a.w), x2a = fmaxf(a.y, a.w);
    float y1b = fminf(b.x, b.z), y2b = fmaxf(b.x, b.z);
    float x1b = fminf(b.y, b.w), x2b = fmaxf(b.y, b.w);
    float ih = fminf(y2a, y2b) - fmaxf(y1a, y1b); ih = fmaxf(ih, 0.0f);
    float iw = fminf(x2a, x2b) - fmaxf(x1a, x1b); iw = fmaxf(iw, 0.0f);
    float inter = ih * iw;
    float aa = (y2a - y1a) * (x2a - x1a);
    float ab = (y2b - y1b) * (x2b - x1b);
    float uni = aa + ab - inter;
    uni = fmaxf(uni, 1e-12f);
    return inter / uni;
}

// ---------------------------------------------------------------------------
// Kernel 1: per-image IoU bitmask matrix (round-5 proven verbatim).
// ---------------------------------------------------------------------------
__global__ __launch_bounds__(256) void iou_masks(
        const float* __restrict__ boxes,    // [B, N, 1, 4]
        u64* __restrict__ masks)            // [B, N, NWORD]
{
    __shared__ float4 bx[N_BOX];            // 16 KB
    const int tid = threadIdx.x;
    const int b  = blockIdx.x >> 6;
    const int rg = blockIdx.x & 63;

    for (int n = tid; n < N_BOX; n += 256)
        bx[n] = ((const float4*)boxes)[b * N_BOX + n];
    __syncthreads();

    const int r = tid >> 4;
    const int w = tid & 15;
    const int i = rg * 16 + r;
    float4 a = bx[i];
    u64 m = 0;
    const int j0 = w * 64;
    for (int jj = 0; jj < 64; ++jj) {
        int j = j0 + jj;
        if (j != i && iou_f(a, bx[j]) > 0.5f) m |= (1ull << jj);
    }
    masks[((size_t)(b * N_BOX + i)) * NWORD + w] = m;
}

// ---------------------------------------------------------------------------
// Kernel 2: transpose scores [B,N,C] -> [B,C,N] (proven tile code).
// ---------------------------------------------------------------------------
__global__ __launch_bounds__(256) void transpose_scores(
        const float* __restrict__ scores,   // [B, N, C]
        float* __restrict__ scoresT)        // [B, C, N]
{
    __shared__ float tile[16 * 17];
    const int tid = threadIdx.x;
    const int t = blockIdx.x;
    const int b  = t / 320;
    const int rm = t % 320;
    const int n0 = (rm / 5) * 16;
    const int c0 = (rm % 5) * 16;
    const int r = tid >> 4, cc = tid & 15;
    tile[r * 17 + cc] = scores[(size_t)(b * N_BOX + n0 + r) * C_CLS + c0 + cc];
    __syncthreads();
    scoresT[(size_t)(b * C_CLS + c0 + r) * N_BOX + n0 + cc] = tile[cc * 17 + r];
}

// ---------------------------------------------------------------------------
// Kernel 3: register/shuffle bitonic sort (round-8 proven), 2 classes per
// 512-thread block; sorted keys + nvalid written to workspace.
// ---------------------------------------------------------------------------
__global__ __launch_bounds__(512) void sort_classes(
        const float* __restrict__ scoresT,  // [B, C, N]
        u64* __restrict__ sorted,           // [B*C, N]
        int* __restrict__ nvalid_arr)       // [B*C]
{
    __shared__ u64 key[2][N_BOX];           // 16 KB (only for j>=256 stages)
    __shared__ int sh_nvalid[2];

    const int tid  = threadIdx.x;
    const int half = tid >> 8;
    const int lt   = tid & 255;
    const int lane = tid & 63;
    const int b  = blockIdx.x / (C_CLS / 2);
    const int c  = (blockIdx.x % (C_CLS / 2)) * 2 + half;
    const int cls = b * C_CLS + c;

    if (lt == 0) sh_nvalid[half] = 0;
    __syncthreads();

    u64 r[4];
    {
        const float4 s4 = ((const float4*)(scoresT + ((size_t)cls << 10)))[lt];
        float sv[4] = {s4.x, s4.y, s4.z, s4.w};
        int lv = 0;
        #pragma unroll
        for (int q = 0; q < 4; ++q) {
            bool valid = sv[q] > 0.001f;               // SCORE_THR
            float s = valid ? sv[q] : NEGF;
            int v = lt * 4 + q;
            r[q] = ((u64)ford(s) << 32) | (u32)(N_BOX - 1 - v);  // stable ties
            lv += valid ? 1 : 0;
        }
        if (lv) atomicAdd(&sh_nvalid[half], lv);
    }

    #define CE(a, b, d) { u64 _mx = (a) > (b) ? (a) : (b); \
                          u64 _mn = (a) > (b) ? (b) : (a); \
                          (a) = (d) ? _mx : _mn; (b) = (d) ? _mn : _mx; }
    CE(r[0], r[1], true); CE(r[2], r[3], false);

    for (int k = 4; k <= N_BOX; k <<= 1) {
        const bool d = ((lt & (k >> 2)) == 0);
        for (int j = k >> 1; j > 0; j >>= 1) {
            if (j >= 256) {                          // cross-wave: LDS stage
                __syncthreads();
                #pragma unroll
                for (int q = 0; q < 4; ++q) key[half][lt * 4 + q] = r[q];
                __syncthreads();
                const bool upper = ((lt * 4) & j) != 0;
                #pragma unroll
                for (int q = 0; q < 4; ++q) {
                    u64 pv = key[half][(lt * 4 + q) ^ j];
                    u64 mx = r[q] > pv ? r[q] : pv;
                    u64 mn = r[q] > pv ? pv : r[q];
                    r[q] = (d != upper) ? mx : mn;
                }
            } else if (j >= 4) {                     // intra-wave: shuffle
                const int dl = j >> 2;
                const bool upper = (lane & dl) != 0;
                #pragma unroll
                for (int q = 0; q < 4; ++q) {
                    u64 pv = __shfl_xor(r[q], dl);
                    u64 mx = r[q] > pv ? r[q] : pv;
                    u64 mn = r[q] > pv ? pv : r[q];
                    r[q] = (d != upper) ? mx : mn;
                }
            } else if (j == 2) {
                CE(r[0], r[2], d); CE(r[1], r[3], d);
            } else {
                CE(r[0], r[1], d); CE(r[2], r[3], d);
            }
        }
    }
    #undef CE

    u64* outk = sorted + ((size_t)cls << 10);
    #pragma unroll
    for (int q = 0; q < 4; ++q) outk[lt * 4 + q] = r[q];
    if (lt == 0) nvalid_arr[cls] = sh_nvalid[half];
}

// ---------------------------------------------------------------------------
// Kernel 4: greedy NMS, 4 classes per 256-thread block (one wave each, no
// __syncthreads). Per 64-candidate window: prefetch ALL 64 mask rows into
// LDS with 16 independent loads (ONE memory round-trip per window instead of
// one dependent trip per batch); then round-9-proven ballot resolution with
// rows read from LDS.
// ---------------------------------------------------------------------------
__global__ __launch_bounds__(256) void greedy_classes(
        const u64* __restrict__ sorted,     // [B*C, N]
        const int* __restrict__ nvalid_arr, // [B*C]
        const u64* __restrict__ masks,      // [B, N, NWORD]
        float* __restrict__ ws_score,       // [B*C*K_PER]
        int*   __restrict__ ws_idx)         // [B*C*K_PER]
{
    __shared__ u64 rows[4][64][NWORD];      // 32 KB — per-wave row cache
    __shared__ int kept_t[4][K_PER];

    const int tid = threadIdx.x;
    const int wv = tid >> 6;                // wave = class slot
    const int lane = tid & 63;
    const int cls = blockIdx.x * 4 + wv;    // b*80 + c
    const int b = cls / C_CLS;
    const int w16 = lane & 15;
    const int sslot = lane >> 4;            // 0..3
    const u64* mrow = masks + (size_t)b * N_BOX * NWORD;
    const u64* ks = sorted + ((size_t)cls << 10);
    const int nvalid = nvalid_arr[cls];
    u64 sup = 0;                            // lanes 0..15 hold suppressed words
    int kept = 0;

    for (int bt = 0; bt < nvalid && kept < K_PER; bt += 64) {
        int t = bt + lane;
        bool in = t < nvalid;
        u64 kv = ks[t & (N_BOX - 1)];
        int idx = (N_BOX - 1) - (int)(u32)(kv & 0xFFFFFFFFu);
        // prefetch all 64 rows of this window into LDS (independent loads)
        #pragma unroll
        for (int p = 0; p < 16; ++p) {
            int rr = p * 4 + sslot;         // row 0..63
            int ir = __shfl(idx, rr);
            u64 w = ((bt + rr) < nvalid) ? mrow[(size_t)ir * NWORD + w16] : 0;
            rows[wv][rr][w16] = w;
        }
        __builtin_amdgcn_wave_barrier();

        u64 window = __ballot(in);
        while (window && kept < K_PER) {
            u64 supw = __shfl(sup, idx >> 6);
            bool sbit = (supw >> (idx & 63)) & 1ull;
            u64 alive = __ballot(in && !sbit) & window;
            if (!alive) break;
            // extract up to 8 leading alive candidates (wave-uniform)
            int ts[8], nb = 0, tlast = 0;
            {
                u64 am = alive;
                #pragma unroll
                for (int r2 = 0; r2 < 8; ++r2) {
                    if (am) {
                        ts[r2] = __ffsll((long long)am) - 1;
                        am &= am - 1; tlast = ts[r2]; nb = r2 + 1;
                    } else ts[r2] = tlast;
                }
            }
            int bi[8];
            #pragma unroll
            for (int r2 = 0; r2 < 8; ++r2) bi[r2] = __shfl(idx, ts[r2]);
            // rows from the LDS cache (ts are wave-uniform)
            u64 row0 = (sslot < nb)     ? rows[wv][ts[sslot]][w16]     : 0;
            u64 row1 = (sslot + 4 < nb) ? rows[wv][ts[sslot + 4]][w16] : 0;
            // conflict matrix via pipelined ballots (round-9 proven)
            u64 cb0[8], cb1[8];
            #pragma unroll
            for (int r2 = 1; r2 < 8; ++r2) {
                int wq = bi[r2] >> 6, bq = bi[r2] & 63;
                cb0[r2] = __ballot(((row0 >> bq) & 1ull) && (w16 == wq));
                cb1[r2] = __ballot(((row1 >> bq) & 1ull) && (w16 == wq));
            }
            // progressive accept in pure VALU (round-9 proven)
            bool acc[8]; acc[0] = true;
            #pragma unroll
            for (int r2 = 1; r2 < 8; ++r2) {
                bool sup_r = false;
                if (r2 < nb) {
                    int wq = bi[r2] >> 6;
                    #pragma unroll
                    for (int s = 0; s < 7; ++s) {
                        if (s < r2 && acc[s]) {
                            u64 cb = (s < 4) ? cb0[r2] : cb1[r2];
                            int bitpos = (s & 3) * 16 + wq;
                            sup_r = sup_r || (((cb >> bitpos) & 1ull) != 0);
                        }
                    }
                }
                acc[r2] = (r2 < nb) && !sup_r;
            }
            // commit sup via 2 shfl_xor OR-reduces (round-9 proven)
            u64 contrib = ((sslot < nb && acc[sslot]) ? row0 : 0) |
                          ((sslot + 4 < nb && acc[sslot + 4]) ? row1 : 0);
            contrib |= __shfl_xor(contrib, 16);
            contrib |= __shfl_xor(contrib, 32);
            if (lane < NWORD) sup |= contrib;
            #pragma unroll
            for (int r2 = 0; r2 < 8; ++r2) {
                if (r2 < nb && acc[r2] && kept < K_PER) {
                    if (lane == 0) kept_t[wv][kept] = bt + ts[r2];
                    kept++;
                }
            }
            window &= ~((2ull << tlast) - 1ull);
        }
    }
    __builtin_amdgcn_wave_barrier();

    for (int i = lane; i < K_PER; i += 64) {
        int ob = cls * K_PER + i;
        if (i < kept) {
            u64 k = ks[kept_t[wv][i]];
            ws_score[ob] = funord((u32)(k >> 32));
            ws_idx[ob]   = (N_BOX - 1) - (int)(u32)(k & 0xFFFFFFFFu);
        } else {
            ws_score[ob] = NEGF;
            ws_idx[ob]   = 0;
        }
    }
}

// ---------------------------------------------------------------------------
// Kernel 5: final top-300 per image (round-9 proven verbatim).
// ---------------------------------------------------------------------------
__global__ __launch_bounds__(1024) void final_topk(
        const float* __restrict__ ws_score,
        const int*   __restrict__ ws_idx,
        const float* __restrict__ boxes,    // [B, N, 1, 4]
        float* __restrict__ out)
{
    __shared__ u32 skey[NCAND];             // 32 KB
    __shared__ u32 hist4[256 * 4];          // 4 KB
    __shared__ u64 list[512];
    __shared__ int sh_sel;
    __shared__ u32 sh_need;
    __shared__ int sh_cnt, sh_valid;

    const int tid = threadIdx.x;
    const int b = blockIdx.x;
    const int base = b * NCAND;

    if (tid == 0) { sh_cnt = 0; sh_valid = 0; }
    for (int i = tid; i < NCAND; i += 1024)
        skey[i] = ford(ws_score[base + i]);
    if (tid < 512) list[tid] = 0;
    hist4[tid] = 0;
    __syncthreads();

    u64 prefix = 0;
    u32 need = K_TOT;
    const int rounds[6] = {7, 6, 5, 4, 1, 0};
    const int slot = tid & 3;

    for (int rd = 0; rd < 6; ++rd) {
        const int d = rounds[rd];
        for (int i = tid; i < NCAND; i += 1024) {
            u64 k = ((u64)skey[i] << 32) | (u32)(M_SEL - 1 - i);
            // d==7 guard: shift by 64 is UB (the round-3/4 crash)
            bool match = (d == 7) || (((k ^ prefix) >> (8 * (d + 1))) == 0);
            if (match)
                atomicAdd(&hist4[(((u32)(k >> (8 * d)) & 0xFFu) << 2) | slot], 1u);
        }
        __syncthreads();
        if (tid < 64) {
            const int l = tid;
            u32 h[4];
            #pragma unroll
            for (int q = 0; q < 4; ++q) {
                int bin = 4 * l + q;
                h[q] = hist4[bin * 4 + 0] + hist4[bin * 4 + 1]
                     + hist4[bin * 4 + 2] + hist4[bin * 4 + 3];
                hist4[bin * 4 + 0] = 0; hist4[bin * 4 + 1] = 0;
                hist4[bin * 4 + 2] = 0; hist4[bin * 4 + 3] = 0;
            }
            u32 s3 = h[3], s2 = h[2] + s3, s1 = h[1] + s2, s0 = h[0] + s1;
            u32 tot = s0, S = tot;
            #pragma unroll
            for (int off = 1; off < 64; off <<= 1) {
                u32 t = __shfl(S, (l + off) & 63);
                if (l + off < 64) S += t;
            }
            u32 T = S - tot;
            u32 sv0 = s0 + T, sv1 = s1 + T, sv2 = s2 + T, sv3 = s3 + T;
            if (sv0 >= need && sv1 < need) { sh_sel = 4*l;     sh_need = need - sv1; }
            if (sv1 >= need && sv2 < need) { sh_sel = 4*l + 1; sh_need = need - sv2; }
            if (sv2 >= need && sv3 < need) { sh_sel = 4*l + 2; sh_need = need - sv3; }
            if (sv3 >= need && T   < need) { sh_sel = 4*l + 3; sh_need = need - T;   }
        }
        __syncthreads();
        prefix |= ((u64)(u32)sh_sel) << (8 * d);
        need = sh_need;
        __syncthreads();
    }

    for (int i = tid; i < NCAND; i += 1024) {
        u64 k = ((u64)skey[i] << 32) | (u32)(M_SEL - 1 - i);
        if (k >= prefix) {
            int p = atomicAdd(&sh_cnt, 1);
            if (p < 512) list[p] = k;
        }
    }
    __syncthreads();

    // one-wave register bitonic sort of list[512], descending (pads 0 last)
    if (tid < 64) {
        const int l = tid;
        u64 e[8];
        #pragma unroll
        for (int q = 0; q < 8; ++q) e[q] = list[l * 8 + q];
        #define CE2(a, b, dd) { u64 _mx = (a) > (b) ? (a) : (b); \
                                u64 _mn = (a) > (b) ? (b) : (a); \
                                (a) = (dd) ? _mx : _mn; (b) = (dd) ? _mn : _mx; }
        CE2(e[0], e[1], true);  CE2(e[2], e[3], false);
        CE2(e[4], e[5], true);  CE2(e[6], e[7], false);
        CE2(e[0], e[2], true);  CE2(e[1], e[3], true);
        CE2(e[4], e[6], false); CE2(e[5], e[7], false);
        CE2(e[0], e[1], true);  CE2(e[2], e[3], true);
        CE2(e[4], e[5], false); CE2(e[6], e[7], false);
        for (int k = 8; k <= 512; k <<= 1) {
            const bool d = ((l & (k >> 3)) == 0);
            for (int j = k >> 1; j >= 8; j >>= 1) {
                const int dl = j >> 3;
                const bool upper = (l & dl) != 0;
                #pragma unroll
                for (int q = 0; q < 8; ++q) {
                    u64 pv = __shfl_xor(e[q], dl);
                    u64 mx = e[q] > pv ? e[q] : pv;
                    u64 mn = e[q] > pv ? pv : e[q];
                    e[q] = (d != upper) ? mx : mn;
                }
            }
            CE2(e[0], e[4], d); CE2(e[1], e[5], d);
            CE2(e[2], e[6], d); CE2(e[3], e[7], d);
            CE2(e[0], e[2], d); CE2(e[1], e[3], d);
            CE2(e[4], e[6], d); CE2(e[5], e[7], d);
            CE2(e[0], e[1], d); CE2(e[2], e[3], d);
            CE2(e[4], e[5], d); CE2(e[6], e[7], d);
        }
        #undef CE2
        #pragma unroll
        for (int q = 0; q < 8; ++q) list[l * 8 + q] = e[q];
    }
    __syncthreads();

    float* out_s = out;                         // [B,300]
    float* out_b = out + B_IMG * K_TOT;         // [B,300,4]
    float* out_c = out + B_IMG * K_TOT * 5;     // [B,300]
    float* out_n = out + B_IMG * K_TOT * 6;     // [B]

    for (int i = tid; i < K_TOT; i += 1024) {
        u64 k = list[i];
        float s = funord((u32)(k >> 32));
        int flat = (M_SEL - 1) - (int)(u32)(k & 0xFFFFFFFFu);
        bool valid = s > (-5e29f);              // top_s > NEG/2
        float os = 0.0f, oc = 0.0f;
        float4 ob = make_float4(0.0f, 0.0f, 0.0f, 0.0f);
        if (valid && flat < NCAND) {
            int cc = flat / K_PER;
            int n  = ws_idx[base + flat];
            float4 bb = ((const float4*)boxes)[b * N_BOX + n];
            os = s;
            oc = (float)cc;
            ob.x = fminf(fmaxf(bb.x, 0.0f), 1.0f);
            ob.y = fminf(fmaxf(bb.y, 0.0f), 1.0f);
            ob.z = fminf(fmaxf(bb.z, 0.0f), 1.0f);
            ob.w = fminf(fmaxf(bb.w, 0.0f), 1.0f);
            atomicAdd(&sh_valid, 1);
        }
        out_s[b * K_TOT + i] = os;
        ((float4*)out_b)[b * K_TOT + i] = ob;
        out_c[b * K_TOT + i] = oc;
    }
    __syncthreads();
    if (tid == 0) out_n[b] = (float)sh_valid;
}

extern "C" void kernel_launch(void* const* d_in, const int* in_sizes, int n_in,
                              void* d_out, int out_size, void* d_ws, size_t ws_size,
                              hipStream_t stream) {
    const float* scores = (const float*)d_in[0];   // [4,1024,80]
    const float* boxes  = (const float*)d_in[1];   // [4,1024,1,4]

    char* ws = (char*)d_ws;                        // 4,713,728 B (round-7 proven)
    float* scoresT    = (float*)(ws + OFF_SCOREST);
    u64*   masks      = (u64*)  (ws + OFF_MASKS);
    u64*   sorted     = (u64*)  (ws + OFF_SORTED);
    int*   nvalid_arr = (int*)  (ws + OFF_NVALID);
    float* ws_score   = (float*)(ws + OFF_WSCORE);
    int*   ws_idx     = (int*)  (ws + OFF_WSIDX);

    iou_masks<<<dim3(256), dim3(256), 0, stream>>>(boxes, masks);
    transpose_scores<<<dim3(1280), dim3(256), 0, stream>>>(scores, scoresT);
    sort_classes<<<dim3(B_IMG * (C_CLS / 2)), dim3(512), 0, stream>>>(
        scoresT, sorted, nvalid_arr);
    greedy_classes<<<dim3(B_IMG * C_CLS / 4), dim3(256), 0, stream>>>(
        sorted, nvalid_arr, masks, ws_score, ws_idx);
    final_topk<<<dim3(B_IMG), dim3(1024), 0, stream>>>(
        ws_score, ws_idx, boxes, (float*)d_out);
}

// Round 11
// 134.009 us; speedup vs baseline: 1.1278x; 1.1278x over previous
//
#include <hip/hip_runtime.h>
#include <stdint.h>

#define N_BOX 1024
#define C_CLS 80
#define B_IMG 4
#define K_PER 100
#define K_TOT 300
#define NEGF  (-1e30f)
#define NWORD 16                 // 1024 bits / 64
#define NCAND (C_CLS * K_PER)    // 8000 candidates per image
#define M_SEL 8192               // flat-index packing base for final top-k

// workspace layout (bytes) — 4,713,728 total (round-7/10 proven footprint)
#define OFF_SCOREST 0            // [B][C][N] f32          1,310,720
#define OFF_MASKS   1310720      // [B][N][NWORD] u64        524,288
#define OFF_SORTED  1835008      // [B*C][N] u64           2,621,440
#define OFF_NVALID  4456448      // [B*C] i32                  1,280
#define OFF_WSCORE  4457728      // [B*C][K_PER] f32         128,000
#define OFF_WSIDX   4585728      // [B*C][K_PER] i32         128,000

typedef unsigned long long u64;
typedef unsigned int u32;

// ---- monotone float <-> ordered-uint mapping (total order, bit-exact) ----
__device__ __forceinline__ u32 ford(float f) {
    u32 u = __float_as_uint(f);
    return (u & 0x80000000u) ? ~u : (u | 0x80000000u);
}
__device__ __forceinline__ float funord(u32 o) {
    u32 u = (o & 0x80000000u) ? (o ^ 0x80000000u) : ~o;
    return __uint_as_float(u);
}

// IoU matching the numpy/jax float32 arithmetic exactly: no fma contraction.
__device__ __forceinline__ float iou_f(float4 a, float4 b) {
#pragma clang fp contract(off)
    float y1a = fminf(a.x, a.z), y2a = fmaxf(a.x, a.z);
    float x1a = fminf(a.y, a.w), x2a = fmaxf(a.y, a.w);
    float y1b = fminf(b.x, b.z), y2b = fmaxf(b.x, b.z);
    float x1b = fminf(b.y, b.w), x2b = fmaxf(b.y, b.w);
    float ih = fminf(y2a, y2b) - fmaxf(y1a, y1b); ih = fmaxf(ih, 0.0f);
    float iw = fminf(x2a, x2b) - fmaxf(x1a, x1b); iw = fmaxf(iw, 0.0f);
    float inter = ih * iw;
    float aa = (y2a - y1a) * (x2a - x1a);
    float ab = (y2b - y1b) * (x2b - x1b);
    float uni = aa + ab - inter;
    uni = fmaxf(uni, 1e-12f);
    return inter / uni;
}

// ---------------------------------------------------------------------------
// Kernel 1 (fused prep, round-8 proven): blocks [0,256) = per-image IoU
// bitmask matrix; blocks [256,1536) = transpose scores [B,N,C] -> [B,C,N].
// ---------------------------------------------------------------------------
__global__ __launch_bounds__(256) void prep_kernel(
        const float* __restrict__ scores,   // [B, N, C]
        const float* __restrict__ boxes,    // [B, N, 1, 4]
        u64*   __restrict__ masks,          // [B, N, NWORD]
        float* __restrict__ scoresT)        // [B, C, N]
{
    __shared__ float4 bx[N_BOX];            // 16 KB (mask path); reused as tile
    const int tid = threadIdx.x;

    if (blockIdx.x < 256) {
        const int b  = blockIdx.x >> 6;
        const int rg = blockIdx.x & 63;
        for (int n = tid; n < N_BOX; n += 256)
            bx[n] = ((const float4*)boxes)[b * N_BOX + n];
        __syncthreads();

        const int r = tid >> 4;
        const int w = tid & 15;
        const int i = rg * 16 + r;
        float4 a = bx[i];
        u64 m = 0;
        const int j0 = w * 64;
        for (int jj = 0; jj < 64; ++jj) {
            int j = j0 + jj;
            if (j != i && iou_f(a, bx[j]) > 0.5f) m |= (1ull << jj);
        }
        masks[((size_t)(b * N_BOX + i)) * NWORD + w] = m;
    } else {
        float* tile = (float*)bx;               // [16][17]
        const int t = blockIdx.x - 256;
        const int b  = t / 320;
        const int rm = t % 320;
        const int n0 = (rm / 5) * 16;
        const int c0 = (rm % 5) * 16;
        const int r = tid >> 4, cc = tid & 15;
        tile[r * 17 + cc] = scores[(size_t)(b * N_BOX + n0 + r) * C_CLS + c0 + cc];
        __syncthreads();
        scoresT[(size_t)(b * C_CLS + c0 + r) * N_BOX + n0 + cc] = tile[cc * 17 + r];
    }
}

// ---------------------------------------------------------------------------
// Kernel 2: register/shuffle bitonic sort (round-10 proven verbatim).
// ---------------------------------------------------------------------------
__global__ __launch_bounds__(512) void sort_classes(
        const float* __restrict__ scoresT,  // [B, C, N]
        u64* __restrict__ sorted,           // [B*C, N]
        int* __restrict__ nvalid_arr)       // [B*C]
{
    __shared__ u64 key[2][N_BOX];           // 16 KB (only for j>=256 stages)
    __shared__ int sh_nvalid[2];

    const int tid  = threadIdx.x;
    const int half = tid >> 8;
    const int lt   = tid & 255;
    const int lane = tid & 63;
    const int b  = blockIdx.x / (C_CLS / 2);
    const int c  = (blockIdx.x % (C_CLS / 2)) * 2 + half;
    const int cls = b * C_CLS + c;

    if (lt == 0) sh_nvalid[half] = 0;
    __syncthreads();

    u64 r[4];
    {
        const float4 s4 = ((const float4*)(scoresT + ((size_t)cls << 10)))[lt];
        float sv[4] = {s4.x, s4.y, s4.z, s4.w};
        int lv = 0;
        #pragma unroll
        for (int q = 0; q < 4; ++q) {
            bool valid = sv[q] > 0.001f;               // SCORE_THR
            float s = valid ? sv[q] : NEGF;
            int v = lt * 4 + q;
            r[q] = ((u64)ford(s) << 32) | (u32)(N_BOX - 1 - v);  // stable ties
            lv += valid ? 1 : 0;
        }
        if (lv) atomicAdd(&sh_nvalid[half], lv);
    }

    #define CE(a, b, d) { u64 _mx = (a) > (b) ? (a) : (b); \
                          u64 _mn = (a) > (b) ? (b) : (a); \
                          (a) = (d) ? _mx : _mn; (b) = (d) ? _mn : _mx; }
    CE(r[0], r[1], true); CE(r[2], r[3], false);

    for (int k = 4; k <= N_BOX; k <<= 1) {
        const bool d = ((lt & (k >> 2)) == 0);
        for (int j = k >> 1; j > 0; j >>= 1) {
            if (j >= 256) {                          // cross-wave: LDS stage
                __syncthreads();
                #pragma unroll
                for (int q = 0; q < 4; ++q) key[half][lt * 4 + q] = r[q];
                __syncthreads();
                const bool upper = ((lt * 4) & j) != 0;
                #pragma unroll
                for (int q = 0; q < 4; ++q) {
                    u64 pv = key[half][(lt * 4 + q) ^ j];
                    u64 mx = r[q] > pv ? r[q] : pv;
                    u64 mn = r[q] > pv ? pv : r[q];
                    r[q] = (d != upper) ? mx : mn;
                }
            } else if (j >= 4) {                     // intra-wave: shuffle
                const int dl = j >> 2;
                const bool upper = (lane & dl) != 0;
                #pragma unroll
                for (int q = 0; q < 4; ++q) {
                    u64 pv = __shfl_xor(r[q], dl);
                    u64 mx = r[q] > pv ? r[q] : pv;
                    u64 mn = r[q] > pv ? pv : r[q];
                    r[q] = (d != upper) ? mx : mn;
                }
            } else if (j == 2) {
                CE(r[0], r[2], d); CE(r[1], r[3], d);
            } else {
                CE(r[0], r[1], d); CE(r[2], r[3], d);
            }
        }
    }
    #undef CE

    u64* outk = sorted + ((size_t)cls << 10);
    #pragma unroll
    for (int q = 0; q < 4; ++q) outk[lt * 4 + q] = r[q];
    if (lt == 0) nvalid_arr[cls] = sh_nvalid[half];
}

// ---------------------------------------------------------------------------
// Kernel 3: greedy NMS, accept-only serial iterations. 4 classes per block
// (one wave each, no __syncthreads). Per 64-window: prefetch rows to LDS,
// ext-check vs sup, then: first pending bit is ALWAYS greedy-accepted ->
// one LDS row read + one ballot eliminates every candidate it suppresses.
// Serial iterations = number of accepts (<=100), not number of alive.
// ---------------------------------------------------------------------------
__global__ __launch_bounds__(256) void greedy_classes(
        const u64* __restrict__ sorted,     // [B*C, N]
        const int* __restrict__ nvalid_arr, // [B*C]
        const u64* __restrict__ masks,      // [B, N, NWORD]
        float* __restrict__ ws_score,       // [B*C*K_PER]
        int*   __restrict__ ws_idx)         // [B*C*K_PER]
{
    __shared__ u64 rows[4][64][NWORD];      // 32 KB — per-wave row cache
    __shared__ int kept_t[4][K_PER];

    const int tid = threadIdx.x;
    const int wv = tid >> 6;                // wave = class slot
    const int lane = tid & 63;
    const int cls = blockIdx.x * 4 + wv;    // b*80 + c
    const int b = cls / C_CLS;
    const int w16 = lane & 15;
    const int sslot = lane >> 4;            // 0..3
    const u64* mrow = masks + (size_t)b * N_BOX * NWORD;
    const u64* ks = sorted + ((size_t)cls << 10);
    const int nvalid = nvalid_arr[cls];
    u64 sup = 0;                            // lanes 0..15 hold suppressed words
    int kept = 0;

    for (int bt = 0; bt < nvalid && kept < K_PER; bt += 64) {
        int t = bt + lane;
        bool in = t < nvalid;
        u64 kv = ks[t & (N_BOX - 1)];
        int idx = (N_BOX - 1) - (int)(u32)(kv & 0xFFFFFFFFu);
        const int widx = idx >> 6, bidx = idx & 63;

        // ext check first: skip the prefetch if the window is fully dead
        u64 supw = __shfl(sup, widx);
        bool sbit = (supw >> bidx) & 1ull;
        u64 pending = __ballot(in && !sbit);
        if (!pending) continue;

        // prefetch all 64 rows of this window into LDS (independent loads)
        #pragma unroll
        for (int p = 0; p < 16; ++p) {
            int rr = p * 4 + sslot;         // row 0..63
            int ir = __shfl(idx, rr);
            u64 w = ((bt + rr) < nvalid) ? mrow[(size_t)ir * NWORD + w16] : 0;
            rows[wv][rr][w16] = w;
        }
        __builtin_amdgcn_wave_barrier();

        // accept-only serial loop
        while (pending && kept < K_PER) {
            int t0 = __ffsll((long long)pending) - 1;      // wave-uniform
            if (lane == 0) kept_t[wv][kept] = bt + t0;
            kept++;
            // each lane tests its own candidate against accepted row t0
            u64 wj = rows[wv][t0][widx];
            bool kill = ((wj >> bidx) & 1ull) != 0;
            // accumulate accepted row into sup (lanes 0..15)
            if (lane < NWORD) sup |= rows[wv][t0][w16];
            pending &= ~(1ull << t0);
            pending &= ~__ballot(kill);
        }
    }
    __builtin_amdgcn_wave_barrier();

    for (int i = lane; i < K_PER; i += 64) {
        int ob = cls * K_PER + i;
        if (i < kept) {
            u64 k = ks[kept_t[wv][i]];
            ws_score[ob] = funord((u32)(k >> 32));
            ws_idx[ob]   = (N_BOX - 1) - (int)(u32)(k & 0xFFFFFFFFu);
        } else {
            ws_score[ob] = NEGF;
            ws_idx[ob]   = 0;
        }
    }
}

// ---------------------------------------------------------------------------
// Kernel 4: final top-300 per image (round-9/10 proven verbatim).
// ---------------------------------------------------------------------------
__global__ __launch_bounds__(1024) void final_topk(
        const float* __restrict__ ws_score,
        const int*   __restrict__ ws_idx,
        const float* __restrict__ boxes,    // [B, N, 1, 4]
        float* __restrict__ out)
{
    __shared__ u32 skey[NCAND];             // 32 KB
    __shared__ u32 hist4[256 * 4];          // 4 KB
    __shared__ u64 list[512];
    __shared__ int sh_sel;
    __shared__ u32 sh_need;
    __shared__ int sh_cnt, sh_valid;

    const int tid = threadIdx.x;
    const int b = blockIdx.x;
    const int base = b * NCAND;

    if (tid == 0) { sh_cnt = 0; sh_valid = 0; }
    for (int i = tid; i < NCAND; i += 1024)
        skey[i] = ford(ws_score[base + i]);
    if (tid < 512) list[tid] = 0;
    hist4[tid] = 0;
    __syncthreads();

    u64 prefix = 0;
    u32 need = K_TOT;
    const int rounds[6] = {7, 6, 5, 4, 1, 0};
    const int slot = tid & 3;

    for (int rd = 0; rd < 6; ++rd) {
        const int d = rounds[rd];
        for (int i = tid; i < NCAND; i += 1024) {
            u64 k = ((u64)skey[i] << 32) | (u32)(M_SEL - 1 - i);
            // d==7 guard: shift by 64 is UB (the round-3/4 crash)
            bool match = (d == 7) || (((k ^ prefix) >> (8 * (d + 1))) == 0);
            if (match)
                atomicAdd(&hist4[(((u32)(k >> (8 * d)) & 0xFFu) << 2) | slot], 1u);
        }
        __syncthreads();
        if (tid < 64) {
            const int l = tid;
            u32 h[4];
            #pragma unroll
            for (int q = 0; q < 4; ++q) {
                int bin = 4 * l + q;
                h[q] = hist4[bin * 4 + 0] + hist4[bin * 4 + 1]
                     + hist4[bin * 4 + 2] + hist4[bin * 4 + 3];
                hist4[bin * 4 + 0] = 0; hist4[bin * 4 + 1] = 0;
                hist4[bin * 4 + 2] = 0; hist4[bin * 4 + 3] = 0;
            }
            u32 s3 = h[3], s2 = h[2] + s3, s1 = h[1] + s2, s0 = h[0] + s1;
            u32 tot = s0, S = tot;
            #pragma unroll
            for (int off = 1; off < 64; off <<= 1) {
                u32 t = __shfl(S, (l + off) & 63);
                if (l + off < 64) S += t;
            }
            u32 T = S - tot;
            u32 sv0 = s0 + T, sv1 = s1 + T, sv2 = s2 + T, sv3 = s3 + T;
            if (sv0 >= need && sv1 < need) { sh_sel = 4*l;     sh_need = need - sv1; }
            if (sv1 >= need && sv2 < need) { sh_sel = 4*l + 1; sh_need = need - sv2; }
            if (sv2 >= need && sv3 < need) { sh_sel = 4*l + 2; sh_need = need - sv3; }
            if (sv3 >= need && T   < need) { sh_sel = 4*l + 3; sh_need = need - T;   }
        }
        __syncthreads();
        prefix |= ((u64)(u32)sh_sel) << (8 * d);
        need = sh_need;
        __syncthreads();
    }

    for (int i = tid; i < NCAND; i += 1024) {
        u64 k = ((u64)skey[i] << 32) | (u32)(M_SEL - 1 - i);
        if (k >= prefix) {
            int p = atomicAdd(&sh_cnt, 1);
            if (p < 512) list[p] = k;
        }
    }
    __syncthreads();

    // one-wave register bitonic sort of list[512], descending (pads 0 last)
    if (tid < 64) {
        const int l = tid;
        u64 e[8];
        #pragma unroll
        for (int q = 0; q < 8; ++q) e[q] = list[l * 8 + q];
        #define CE2(a, b, dd) { u64 _mx = (a) > (b) ? (a) : (b); \
                                u64 _mn = (a) > (b) ? (b) : (a); \
                                (a) = (dd) ? _mx : _mn; (b) = (dd) ? _mn : _mx; }
        CE2(e[0], e[1], true);  CE2(e[2], e[3], false);
        CE2(e[4], e[5], true);  CE2(e[6], e[7], false);
        CE2(e[0], e[2], true);  CE2(e[1], e[3], true);
        CE2(e[4], e[6], false); CE2(e[5], e[7], false);
        CE2(e[0], e[1], true);  CE2(e[2], e[3], true);
        CE2(e[4], e[5], false); CE2(e[6], e[7], false);
        for (int k = 8; k <= 512; k <<= 1) {
            const bool d = ((l & (k >> 3)) == 0);
            for (int j = k >> 1; j >= 8; j >>= 1) {
                const int dl = j >> 3;
                const bool upper = (l & dl) != 0;
                #pragma unroll
                for (int q = 0; q < 8; ++q) {
                    u64 pv = __shfl_xor(e[q], dl);
                    u64 mx = e[q] > pv ? e[q] : pv;
                    u64 mn = e[q] > pv ? pv : e[q];
                    e[q] = (d != upper) ? mx : mn;
                }
            }
            CE2(e[0], e[4], d); CE2(e[1], e[5], d);
            CE2(e[2], e[6], d); CE2(e[3], e[7], d);
            CE2(e[0], e[2], d); CE2(e[1], e[3], d);
            CE2(e[4], e[6], d); CE2(e[5], e[7], d);
            CE2(e[0], e[1], d); CE2(e[2], e[3], d);
            CE2(e[4], e[5], d); CE2(e[6], e[7], d);
        }
        #undef CE2
        #pragma unroll
        for (int q = 0; q < 8; ++q) list[l * 8 + q] = e[q];
    }
    __syncthreads();

    float* out_s = out;                         // [B,300]
    float* out_b = out + B_IMG * K_TOT;         // [B,300,4]
    float* out_c = out + B_IMG * K_TOT * 5;     // [B,300]
    float* out_n = out + B_IMG * K_TOT * 6;     // [B]

    for (int i = tid; i < K_TOT; i += 1024) {
        u64 k = list[i];
        float s = funord((u32)(k >> 32));
        int flat = (M_SEL - 1) - (int)(u32)(k & 0xFFFFFFFFu);
        bool valid = s > (-5e29f);              // top_s > NEG/2
        float os = 0.0f, oc = 0.0f;
        float4 ob = make_float4(0.0f, 0.0f, 0.0f, 0.0f);
        if (valid && flat < NCAND) {
            int cc = flat / K_PER;
            int n  = ws_idx[base + flat];
            float4 bb = ((const float4*)boxes)[b * N_BOX + n];
            os = s;
            oc = (float)cc;
            ob.x = fminf(fmaxf(bb.x, 0.0f), 1.0f);
            ob.y = fminf(fmaxf(bb.y, 0.0f), 1.0f);
            ob.z = fminf(fmaxf(bb.z, 0.0f), 1.0f);
            ob.w = fminf(fmaxf(bb.w, 0.0f), 1.0f);
            atomicAdd(&sh_valid, 1);
        }
        out_s[b * K_TOT + i] = os;
        ((float4*)out_b)[b * K_TOT + i] = ob;
        out_c[b * K_TOT + i] = oc;
    }
    __syncthreads();
    if (tid == 0) out_n[b] = (float)sh_valid;
}

extern "C" void kernel_launch(void* const* d_in, const int* in_sizes, int n_in,
                              void* d_out, int out_size, void* d_ws, size_t ws_size,
                              hipStream_t stream) {
    const float* scores = (const float*)d_in[0];   // [4,1024,80]
    const float* boxes  = (const float*)d_in[1];   // [4,1024,1,4]

    char* ws = (char*)d_ws;                        // 4,713,728 B (proven)
    float* scoresT    = (float*)(ws + OFF_SCOREST);
    u64*   masks      = (u64*)  (ws + OFF_MASKS);
    u64*   sorted     = (u64*)  (ws + OFF_SORTED);
    int*   nvalid_arr = (int*)  (ws + OFF_NVALID);
    float* ws_score   = (float*)(ws + OFF_WSCORE);
    int*   ws_idx     = (int*)  (ws + OFF_WSIDX);

    prep_kernel<<<dim3(256 + 1280), dim3(256), 0, stream>>>(scores, boxes, masks, scoresT);
    sort_classes<<<dim3(B_IMG * (C_CLS / 2)), dim3(512), 0, stream>>>(
        scoresT, sorted, nvalid_arr);
    greedy_classes<<<dim3(B_IMG * C_CLS / 4), dim3(256), 0, stream>>>(
        sorted, nvalid_arr, masks, ws_score, ws_idx);
    final_topk<<<dim3(B_IMG), dim3(1024), 0, stream>>>(
        ws_score, ws_idx, boxes, (float*)d_out);
}

// Round 13
// 128.432 us; speedup vs baseline: 1.1768x; 1.0434x over previous
//
#include <hip/hip_runtime.h>
#include <stdint.h>

#define N_BOX 1024
#define C_CLS 80
#define B_IMG 4
#define K_PER 100
#define K_TOT 300
#define NEGF  (-1e30f)
#define NWORD 16                 // 1024 bits / 64
#define NCAND (C_CLS * K_PER)    // 8000 candidates per image
#define M_SEL 8192               // flat-index packing base for final top-k

// workspace layout (bytes) — 2,091,008 total (round-8 proven footprint)
#define OFF_SCOREST 0            // [B][C][N] f32          1,310,720
#define OFF_MASKS   1310720      // [B][N][NWORD] u64        524,288
#define OFF_WSCORE  1835008      // [B*C][K_PER] f32         128,000
#define OFF_WSIDX   1963008      // [B*C][K_PER] i32         128,000

typedef unsigned long long u64;
typedef unsigned int u32;

// ---- monotone float <-> ordered-uint mapping (total order, bit-exact) ----
__device__ __forceinline__ u32 ford(float f) {
    u32 u = __float_as_uint(f);
    return (u & 0x80000000u) ? ~u : (u | 0x80000000u);
}
__device__ __forceinline__ float funord(u32 o) {
    u32 u = (o & 0x80000000u) ? (o ^ 0x80000000u) : ~o;
    return __uint_as_float(u);
}

// ---------------------------------------------------------------------------
// Kernel 1 (fused prep): blocks [0,256) = per-image IoU bitmask matrix with
// HOISTED canonicalization (canonical corners + area computed once per box —
// min/max are exact so rounding is identical to the reference);
// blocks [256,1536) = transpose scores [B,N,C] -> [B,C,N] (proven tiles).
// NOTE: `#pragma clang fp contract(off)` must open a compound statement —
// braces added (the round-12 compile failure).
// ---------------------------------------------------------------------------
__global__ __launch_bounds__(256) void prep_kernel(
        const float* __restrict__ scores,   // [B, N, C]
        const float* __restrict__ boxes,    // [B, N, 1, 4]
        u64*   __restrict__ masks,          // [B, N, NWORD]
        float* __restrict__ scoresT)        // [B, C, N]
{
    __shared__ float4 bx[N_BOX];            // canonical y1,x1,y2,x2 (16 KB)
    __shared__ float  ar[N_BOX];            // area (4 KB)
    const int tid = threadIdx.x;

    if (blockIdx.x < 256) {
        const int b  = blockIdx.x >> 6;
        const int rg = blockIdx.x & 63;
        for (int n = tid; n < N_BOX; n += 256) {
            float4 v = ((const float4*)boxes)[b * N_BOX + n];
            {
#pragma clang fp contract(off)
                float y1 = fminf(v.x, v.z), y2 = fmaxf(v.x, v.z);
                float x1 = fminf(v.y, v.w), x2 = fmaxf(v.y, v.w);
                bx[n] = make_float4(y1, x1, y2, x2);
                ar[n] = (y2 - y1) * (x2 - x1);
            }
        }
        __syncthreads();

        const int r = tid >> 4;
        const int w = tid & 15;
        const int i = rg * 16 + r;
        const float4 a = bx[i];
        const float area_a = ar[i];
        u64 m = 0;
        const int j0 = w * 64;
        for (int jj = 0; jj < 64; ++jj) {
            int j = j0 + jj;
            float4 q = bx[j];
            {
#pragma clang fp contract(off)
                float ih = fminf(a.z, q.z) - fmaxf(a.x, q.x); ih = fmaxf(ih, 0.0f);
                float iw = fminf(a.w, q.w) - fmaxf(a.y, q.y); iw = fmaxf(iw, 0.0f);
                float inter = ih * iw;
                float uni = fmaxf(area_a + ar[j] - inter, 1e-12f);
                if (j != i && (inter / uni) > 0.5f) m |= (1ull << jj);
            }
        }
        masks[((size_t)(b * N_BOX + i)) * NWORD + w] = m;
    } else {
        float* tile = (float*)bx;               // [16][17]
        const int t = blockIdx.x - 256;
        const int b  = t / 320;
        const int rm = t % 320;
        const int n0 = (rm / 5) * 16;
        const int c0 = (rm % 5) * 16;
        const int r = tid >> 4, cc = tid & 15;
        tile[r * 17 + cc] = scores[(size_t)(b * N_BOX + n0 + r) * C_CLS + c0 + cc];
        __syncthreads();
        scoresT[(size_t)(b * C_CLS + c0 + r) * N_BOX + n0 + cc] = tile[cc * 17 + r];
    }
}

// ---------------------------------------------------------------------------
// Kernel 2 (fused sort+greedy): one block per (image, class-PAIR), 512 thr.
// Each half (256 thr) sorts its class's 1024 packed keys with the proven
// register/shuffle bitonic (3 LDS stages only); keys land in LDS; waves 0/4
// then run the proven ACCEPT-ONLY greedy (serial iterations = #accepts).
// ---------------------------------------------------------------------------
__global__ __launch_bounds__(512) void nms_classes(
        const float* __restrict__ scoresT,  // [B, C, N]
        const u64*   __restrict__ masks,    // [B, N, NWORD]
        float* __restrict__ ws_score,       // [B*C*K_PER]
        int*   __restrict__ ws_idx)         // [B*C*K_PER]
{
    __shared__ u64 key[2][N_BOX];           // 16 KB
    __shared__ u64 rows[2][64][NWORD];      // 16 KB — per-half row cache
    __shared__ int kept_t[2][K_PER];
    __shared__ int sh_nvalid[2], sh_kept[2];

    const int tid  = threadIdx.x;
    const int half = tid >> 8;              // 0/1 = which class of the pair
    const int lt   = tid & 255;             // half-local thread id
    const int lane = tid & 63;
    const int b  = blockIdx.x / (C_CLS / 2);
    const int c  = (blockIdx.x % (C_CLS / 2)) * 2 + half;

    if (lt == 0) { sh_nvalid[half] = 0; sh_kept[half] = 0; }
    __syncthreads();

    // ---- load: thread lt owns elements v = lt*4+q (coalesced float4) ----
    u64 r[4];
    {
        const float4 s4 = ((const float4*)(scoresT + ((size_t)(b * C_CLS + c) << 10)))[lt];
        float sv[4] = {s4.x, s4.y, s4.z, s4.w};
        int lv = 0;
        #pragma unroll
        for (int q = 0; q < 4; ++q) {
            bool valid = sv[q] > 0.001f;               // SCORE_THR
            float s = valid ? sv[q] : NEGF;
            int v = lt * 4 + q;
            r[q] = ((u64)ford(s) << 32) | (u32)(N_BOX - 1 - v);  // stable ties
            lv += valid ? 1 : 0;
        }
        if (lv) atomicAdd(&sh_nvalid[half], lv);
    }

    // ---- register/shuffle bitonic sort, descending (round-8/10 proven) ----
    #define CE(a, b, d) { u64 _mx = (a) > (b) ? (a) : (b); \
                          u64 _mn = (a) > (b) ? (b) : (a); \
                          (a) = (d) ? _mx : _mn; (b) = (d) ? _mn : _mx; }
    CE(r[0], r[1], true); CE(r[2], r[3], false);

    for (int k = 4; k <= N_BOX; k <<= 1) {
        const bool d = ((lt & (k >> 2)) == 0);
        for (int j = k >> 1; j > 0; j >>= 1) {
            if (j >= 256) {                          // cross-wave: LDS stage
                __syncthreads();
                #pragma unroll
                for (int q = 0; q < 4; ++q) key[half][lt * 4 + q] = r[q];
                __syncthreads();
                const bool upper = ((lt * 4) & j) != 0;
                #pragma unroll
                for (int q = 0; q < 4; ++q) {
                    u64 pv = key[half][(lt * 4 + q) ^ j];
                    u64 mx = r[q] > pv ? r[q] : pv;
                    u64 mn = r[q] > pv ? pv : r[q];
                    r[q] = (d != upper) ? mx : mn;
                }
            } else if (j >= 4) {                     // intra-wave: shuffle
                const int dl = j >> 2;
                const bool upper = (lane & dl) != 0;
                #pragma unroll
                for (int q = 0; q < 4; ++q) {
                    u64 pv = __shfl_xor(r[q], dl);
                    u64 mx = r[q] > pv ? r[q] : pv;
                    u64 mn = r[q] > pv ? pv : r[q];
                    r[q] = (d != upper) ? mx : mn;
                }
            } else if (j == 2) {
                CE(r[0], r[2], d); CE(r[1], r[3], d);
            } else {
                CE(r[0], r[1], d); CE(r[2], r[3], d);
            }
        }
    }
    #undef CE

    __syncthreads();
    #pragma unroll
    for (int q = 0; q < 4; ++q) key[half][lt * 4 + q] = r[q];
    __syncthreads();

    // ---- accept-only greedy (round-11 proven): wave 0 -> h0, wave 4 -> h1
    const int wv = tid >> 6;
    if (wv == 0 || wv == 4) {
        const int gh = wv >> 2;
        const int w16 = lane & 15;
        const int sslot = lane >> 4;            // 0..3
        const u64* mrow = masks + (size_t)b * N_BOX * NWORD;
        const int nvalid = sh_nvalid[gh];
        u64 sup = 0;                            // lanes 0..15 hold words
        int kept = 0;

        for (int bt = 0; bt < nvalid && kept < K_PER; bt += 64) {
            int t = bt + lane;
            bool in = t < nvalid;
            u64 kv = key[gh][t & (N_BOX - 1)];
            int idx = (N_BOX - 1) - (int)(u32)(kv & 0xFFFFFFFFu);
            const int widx = idx >> 6, bidx = idx & 63;

            // ext check first: skip prefetch if the window is fully dead
            u64 supw = __shfl(sup, widx);
            bool sbit = (supw >> bidx) & 1ull;
            u64 pending = __ballot(in && !sbit);
            if (!pending) continue;

            // prefetch all 64 rows of this window into LDS
            #pragma unroll
            for (int p = 0; p < 16; ++p) {
                int rr = p * 4 + sslot;         // row 0..63
                int ir = __shfl(idx, rr);
                u64 w = ((bt + rr) < nvalid) ? mrow[(size_t)ir * NWORD + w16] : 0;
                rows[gh][rr][w16] = w;
            }
            __builtin_amdgcn_wave_barrier();

            // accept-only serial loop: first pending bit is ALWAYS accepted
            while (pending && kept < K_PER) {
                int t0 = __ffsll((long long)pending) - 1;      // wave-uniform
                if (lane == 0) kept_t[gh][kept] = bt + t0;
                kept++;
                u64 wj = rows[gh][t0][widx];
                bool kill = ((wj >> bidx) & 1ull) != 0;
                if (lane < NWORD) sup |= rows[gh][t0][w16];
                pending &= ~(1ull << t0);
                pending &= ~__ballot(kill);
            }
        }
        if (lane == 0) sh_kept[gh] = kept;
    }
    __syncthreads();

    const int kept = sh_kept[half];
    if (lt < K_PER) {
        int ob = (b * C_CLS + c) * K_PER + lt;
        if (lt < kept) {
            u64 k = key[half][kept_t[half][lt]];
            ws_score[ob] = funord((u32)(k >> 32));
            ws_idx[ob]   = (N_BOX - 1) - (int)(u32)(k & 0xFFFFFFFFu);
        } else {
            ws_score[ob] = NEGF;
            ws_idx[ob]   = 0;
        }
    }
}

// ---------------------------------------------------------------------------
// Kernel 3: final top-300 per image (round-9/10/11 proven verbatim).
// ---------------------------------------------------------------------------
__global__ __launch_bounds__(1024) void final_topk(
        const float* __restrict__ ws_score,
        const int*   __restrict__ ws_idx,
        const float* __restrict__ boxes,    // [B, N, 1, 4]
        float* __restrict__ out)
{
    __shared__ u32 skey[NCAND];             // 32 KB
    __shared__ u32 hist4[256 * 4];          // 4 KB
    __shared__ u64 list[512];
    __shared__ int sh_sel;
    __shared__ u32 sh_need;
    __shared__ int sh_cnt, sh_valid;

    const int tid = threadIdx.x;
    const int b = blockIdx.x;
    const int base = b * NCAND;

    if (tid == 0) { sh_cnt = 0; sh_valid = 0; }
    for (int i = tid; i < NCAND; i += 1024)
        skey[i] = ford(ws_score[base + i]);
    if (tid < 512) list[tid] = 0;
    hist4[tid] = 0;
    __syncthreads();

    u64 prefix = 0;
    u32 need = K_TOT;
    const int rounds[6] = {7, 6, 5, 4, 1, 0};
    const int slot = tid & 3;

    for (int rd = 0; rd < 6; ++rd) {
        const int d = rounds[rd];
        for (int i = tid; i < NCAND; i += 1024) {
            u64 k = ((u64)skey[i] << 32) | (u32)(M_SEL - 1 - i);
            // d==7 guard: shift by 64 is UB (the round-3/4 crash)
            bool match = (d == 7) || (((k ^ prefix) >> (8 * (d + 1))) == 0);
            if (match)
                atomicAdd(&hist4[(((u32)(k >> (8 * d)) & 0xFFu) << 2) | slot], 1u);
        }
        __syncthreads();
        if (tid < 64) {
            const int l = tid;
            u32 h[4];
            #pragma unroll
            for (int q = 0; q < 4; ++q) {
                int bin = 4 * l + q;
                h[q] = hist4[bin * 4 + 0] + hist4[bin * 4 + 1]
                     + hist4[bin * 4 + 2] + hist4[bin * 4 + 3];
                hist4[bin * 4 + 0] = 0; hist4[bin * 4 + 1] = 0;
                hist4[bin * 4 + 2] = 0; hist4[bin * 4 + 3] = 0;
            }
            u32 s3 = h[3], s2 = h[2] + s3, s1 = h[1] + s2, s0 = h[0] + s1;
            u32 tot = s0, S = tot;
            #pragma unroll
            for (int off = 1; off < 64; off <<= 1) {
                u32 t = __shfl(S, (l + off) & 63);
                if (l + off < 64) S += t;
            }
            u32 T = S - tot;
            u32 sv0 = s0 + T, sv1 = s1 + T, sv2 = s2 + T, sv3 = s3 + T;
            if (sv0 >= need && sv1 < need) { sh_sel = 4*l;     sh_need = need - sv1; }
            if (sv1 >= need && sv2 < need) { sh_sel = 4*l + 1; sh_need = need - sv2; }
            if (sv2 >= need && sv3 < need) { sh_sel = 4*l + 2; sh_need = need - sv3; }
            if (sv3 >= need && T   < need) { sh_sel = 4*l + 3; sh_need = need - T;   }
        }
        __syncthreads();
        prefix |= ((u64)(u32)sh_sel) << (8 * d);
        need = sh_need;
        __syncthreads();
    }

    for (int i = tid; i < NCAND; i += 1024) {
        u64 k = ((u64)skey[i] << 32) | (u32)(M_SEL - 1 - i);
        if (k >= prefix) {
            int p = atomicAdd(&sh_cnt, 1);
            if (p < 512) list[p] = k;
        }
    }
    __syncthreads();

    // one-wave register bitonic sort of list[512], descending (pads 0 last)
    if (tid < 64) {
        const int l = tid;
        u64 e[8];
        #pragma unroll
        for (int q = 0; q < 8; ++q) e[q] = list[l * 8 + q];
        #define CE2(a, b, dd) { u64 _mx = (a) > (b) ? (a) : (b); \
                                u64 _mn = (a) > (b) ? (b) : (a); \
                                (a) = (dd) ? _mx : _mn; (b) = (dd) ? _mn : _mx; }
        CE2(e[0], e[1], true);  CE2(e[2], e[3], false);
        CE2(e[4], e[5], true);  CE2(e[6], e[7], false);
        CE2(e[0], e[2], true);  CE2(e[1], e[3], true);
        CE2(e[4], e[6], false); CE2(e[5], e[7], false);
        CE2(e[0], e[1], true);  CE2(e[2], e[3], true);
        CE2(e[4], e[5], false); CE2(e[6], e[7], false);
        for (int k = 8; k <= 512; k <<= 1) {
            const bool d = ((l & (k >> 3)) == 0);
            for (int j = k >> 1; j >= 8; j >>= 1) {
                const int dl = j >> 3;
                const bool upper = (l & dl) != 0;
                #pragma unroll
                for (int q = 0; q < 8; ++q) {
                    u64 pv = __shfl_xor(e[q], dl);
                    u64 mx = e[q] > pv ? e[q] : pv;
                    u64 mn = e[q] > pv ? pv : e[q];
                    e[q] = (d != upper) ? mx : mn;
                }
            }
            CE2(e[0], e[4], d); CE2(e[1], e[5], d);
            CE2(e[2], e[6], d); CE2(e[3], e[7], d);
            CE2(e[0], e[2], d); CE2(e[1], e[3], d);
            CE2(e[4], e[6], d); CE2(e[5], e[7], d);
            CE2(e[0], e[1], d); CE2(e[2], e[3], d);
            CE2(e[4], e[5], d); CE2(e[6], e[7], d);
        }
        #undef CE2
        #pragma unroll
        for (int q = 0; q < 8; ++q) list[l * 8 + q] = e[q];
    }
    __syncthreads();

    float* out_s = out;                         // [B,300]
    float* out_b = out + B_IMG * K_TOT;         // [B,300,4]
    float* out_c = out + B_IMG * K_TOT * 5;     // [B,300]
    float* out_n = out + B_IMG * K_TOT * 6;     // [B]

    for (int i = tid; i < K_TOT; i += 1024) {
        u64 k = list[i];
        float s = funord((u32)(k >> 32));
        int flat = (M_SEL - 1) - (int)(u32)(k & 0xFFFFFFFFu);
        bool valid = s > (-5e29f);              // top_s > NEG/2
        float os = 0.0f, oc = 0.0f;
        float4 ob = make_float4(0.0f, 0.0f, 0.0f, 0.0f);
        if (valid && flat < NCAND) {
            int cc = flat / K_PER;
            int n  = ws_idx[base + flat];
            float4 bb = ((const float4*)boxes)[b * N_BOX + n];
            os = s;
            oc = (float)cc;
            ob.x = fminf(fmaxf(bb.x, 0.0f), 1.0f);
            ob.y = fminf(fmaxf(bb.y, 0.0f), 1.0f);
            ob.z = fminf(fmaxf(bb.z, 0.0f), 1.0f);
            ob.w = fminf(fmaxf(bb.w, 0.0f), 1.0f);
            atomicAdd(&sh_valid, 1);
        }
        out_s[b * K_TOT + i] = os;
        ((float4*)out_b)[b * K_TOT + i] = ob;
        out_c[b * K_TOT + i] = oc;
    }
    __syncthreads();
    if (tid == 0) out_n[b] = (float)sh_valid;
}

extern "C" void kernel_launch(void* const* d_in, const int* in_sizes, int n_in,
                              void* d_out, int out_size, void* d_ws, size_t ws_size,
                              hipStream_t stream) {
    const float* scores = (const float*)d_in[0];   // [4,1024,80]
    const float* boxes  = (const float*)d_in[1];   // [4,1024,1,4]

    char* ws = (char*)d_ws;                        // 2,091,008 B (proven)
    float* scoresT  = (float*)(ws + OFF_SCOREST);
    u64*   masks    = (u64*)  (ws + OFF_MASKS);
    float* ws_score = (float*)(ws + OFF_WSCORE);
    int*   ws_idx   = (int*)  (ws + OFF_WSIDX);

    prep_kernel<<<dim3(256 + 1280), dim3(256), 0, stream>>>(scores, boxes, masks, scoresT);
    nms_classes<<<dim3(B_IMG * (C_CLS / 2)), dim3(512), 0, stream>>>(
        scoresT, masks, ws_score, ws_idx);
    final_topk<<<dim3(B_IMG), dim3(1024), 0, stream>>>(
        ws_score, ws_idx, boxes, (float*)d_out);
}